// Round 3
// baseline (110.252 us; speedup 1.0000x reference)
//
#include <hip/hip_runtime.h>

// Viterbi trellis quantizer: S=1024 states, K=2 (4 predecessors), CHUNK=4,
// block_size=16 -> T=64 steps/chain, B=4096 chains (16x16 blocks of 1024^2).
//
// Mapping: one 64-lane wave per chain, 4 chains per 256-thread workgroup.
// Grouped-min state M[p] = min_j alpha[p + 256 j] (p in [0,256)) in LDS;
// backpointers 2-bit packed in LDS. Codebook rows for a lane
// (s = 4*lane + c + 256*j) are step-invariant -> PINNED in VGPRs.
//
// R1 evidence: VGPR_Count=64, WRITE_SIZE=5 MB (no scratch writes) -> the
// scheduler REMATERIALIZED the 20 codebook loads inside the 63-step loop
// (L1-hit reloads + addr VALU each step) to hit the 8-waves/EU tier.
// Fix: empty inline-asm with "+v" operands makes remat illegal; the
// __launch_bounds__(256,4) budget (128 VGPR) holds the ~114 live regs.

#define COLS      1024
#define T_STEPS   64
#define REC_SIZE  (1024 * 1024)

__global__ __launch_bounds__(256, 4) void viterbi_q(
    const float* __restrict__ arr,
    const float* __restrict__ cbook,
    float* __restrict__ out)
{
    const int tid   = threadIdx.x;
    const int wid   = tid >> 6;      // wave id in block = chain slot
    const int lane  = tid & 63;
    const int chain = (blockIdx.x << 2) | wid;   // 0..4095
    const int rb    = chain >> 6;    // block-row
    const int cb    = chain & 63;    // block-col

    __shared__ __align__(16) float tile[4][256];   // x chunks for the chain
    __shared__ __align__(16) float Mst[4][256];    // grouped-min state M[p]
    __shared__ unsigned char Jb[4][63 * 64];       // packed backpointers
    __shared__ int st_lds[4][64];                  // traced-back states

    // ---- stage this chain's 16x16 tile into LDS (tile[e], e = r*16 + c) ----
    {
        const int r  = lane >> 2;
        const int c4 = (lane & 3) << 2;
        float4 v = *(const float4*)(arr + (rb * 16 + r) * COLS + cb * 16 + c4);
        *(float4*)&tile[wid][lane << 2] = v;
    }
    // M starts at 0: iteration t=0 then computes alpha0 = cost(x0) exactly.
    *(float4*)&Mst[wid][lane << 2] = make_float4(0.f, 0.f, 0.f, 0.f);

    // ---- codebook rows for this lane's 16 states: s = 4*lane + c + 256*j ----
    float4 a[16];   // -2 * codebook row
    float  nrm[16]; // ||row||^2
    #pragma unroll
    for (int j = 0; j < 4; ++j) {
        #pragma unroll
        for (int c = 0; c < 4; ++c) {
            const int row = (lane << 2) + c + (j << 8);
            float4 v = *(const float4*)(cbook + row * 4);
            nrm[j * 4 + c] = v.x * v.x + v.y * v.y + v.z * v.z + v.w * v.w;
            a[j * 4 + c]   = make_float4(-2.f * v.x, -2.f * v.y,
                                         -2.f * v.z, -2.f * v.w);
        }
    }
    // Pin the codebook into VGPRs: empty asm "modifies" the values, so the
    // scheduler cannot rematerialize the loads inside the loop.
    #pragma unroll
    for (int j = 0; j < 4; ++j) {
        asm volatile(""
            : "+v"(a[j*4+0].x), "+v"(a[j*4+0].y), "+v"(a[j*4+0].z), "+v"(a[j*4+0].w),
              "+v"(a[j*4+1].x), "+v"(a[j*4+1].y), "+v"(a[j*4+1].z), "+v"(a[j*4+1].w),
              "+v"(a[j*4+2].x), "+v"(a[j*4+2].y), "+v"(a[j*4+2].z), "+v"(a[j*4+2].w),
              "+v"(a[j*4+3].x), "+v"(a[j*4+3].y), "+v"(a[j*4+3].z), "+v"(a[j*4+3].w),
              "+v"(nrm[j*4+0]), "+v"(nrm[j*4+1]), "+v"(nrm[j*4+2]), "+v"(nrm[j*4+3]));
    }

    // hoisted LDS pointers
    const float* __restrict__ tilep = &tile[wid][0];
    float* __restrict__ Mp          = &Mst[wid][0];
    unsigned char* __restrict__ Jp  = &Jb[wid][0];

    // ---- forward recursion, t = 0..62: store backpointers J_t ----
    #pragma unroll 1
    for (int t = 0; t < T_STEPS - 1; ++t) {
        float4 xt = *(const float4*)&tilep[t << 2];   // broadcast read
        const float xn = xt.x * xt.x + xt.y * xt.y + xt.z * xt.z + xt.w * xt.w;
        float mj[4];
        #pragma unroll
        for (int j = 0; j < 4; ++j)
            mj[j] = Mp[lane + 64 * j] + xn;

        float nm[4];
        unsigned bp = 0;
        #pragma unroll
        for (int c = 0; c < 4; ++c) {
            float cand[4];
            #pragma unroll
            for (int j = 0; j < 4; ++j) {
                float acc = nrm[j * 4 + c] + mj[j];
                const float4 av = a[j * 4 + c];
                acc = fmaf(av.x, xt.x, acc);
                acc = fmaf(av.y, xt.y, acc);
                acc = fmaf(av.z, xt.z, acc);
                acc = fmaf(av.w, xt.w, acc);
                cand[j] = acc;
            }
            const float v = fminf(fminf(cand[0], cand[1]),
                                  fminf(cand[2], cand[3]));
            // first-min index (jnp.argmin tie semantics)
            const int j = (cand[0] == v) ? 0
                        : (cand[1] == v) ? 1
                        : (cand[2] == v) ? 2 : 3;
            nm[c] = v;
            bp |= (unsigned)j << (2 * c);
        }
        // wave-lockstep: all lanes issued their M reads above before this write
        *(float4*)&Mp[lane << 2] = make_float4(nm[0], nm[1], nm[2], nm[3]);
        Jp[t * 64 + lane] = (unsigned char)bp;
    }

    // ---- final step t = 63: full argmin over alpha_63[0..1023] ----
    int bests;
    {
        const int t = T_STEPS - 1;
        float4 xt = *(const float4*)&tilep[t << 2];
        const float xn = xt.x * xt.x + xt.y * xt.y + xt.z * xt.z + xt.w * xt.w;
        float mj[4];
        #pragma unroll
        for (int j = 0; j < 4; ++j)
            mj[j] = Mp[lane + 64 * j] + xn;

        float bv = 3.4e38f;
        int   bs = 0;
        #pragma unroll
        for (int j = 0; j < 4; ++j) {      // s ascends with (j, c): first-min ok
            #pragma unroll
            for (int c = 0; c < 4; ++c) {
                float acc = nrm[j * 4 + c] + mj[j];
                const float4 av = a[j * 4 + c];
                acc = fmaf(av.x, xt.x, acc);
                acc = fmaf(av.y, xt.y, acc);
                acc = fmaf(av.z, xt.z, acc);
                acc = fmaf(av.w, xt.w, acc);
                if (acc < bv) { bv = acc; bs = (lane << 2) + c + (j << 8); }
            }
        }
        // lexicographic (value, state) butterfly reduction across the wave
        #pragma unroll
        for (int off = 32; off > 0; off >>= 1) {
            const float ov = __shfl_xor(bv, off, 64);
            const int   os = __shfl_xor(bs, off, 64);
            if (ov < bv || (ov == bv && os < bs)) { bv = ov; bs = os; }
        }
        bests = bs;
    }

    // ---- traceback (serial, lane 0 of each wave) ----
    if (lane == 0) {
        int s = bests;
        st_lds[wid][T_STEPS - 1] = s;
        for (int i = T_STEPS - 2; i >= 0; --i) {
            const int p = s >> 2;
            const unsigned byte = Jp[i * 64 + (p >> 2)];
            const int j = (byte >> (2 * (p & 3))) & 3;
            s = p + (j << 8);
            st_lds[wid][i] = s;
        }
    }
    __syncthreads();

    // ---- outputs: lane i handles step t = i ----
    const int st = st_lds[wid][lane];
    // states_out flat: REC_SIZE + chain*64 + t   (stored as float values)
    out[REC_SIZE + chain * 64 + lane] = (float)st;
    // rec: step t covers elements e = 4t..4t+3 -> row t>>2, cols 4*(t&3)..+3
    const float4 v = *(const float4*)(cbook + st * 4);
    const int r  = lane >> 2;
    const int c4 = (lane & 3) << 2;
    *(float4*)(out + (rb * 16 + r) * COLS + cb * 16 + c4) = v;
}

extern "C" void kernel_launch(void* const* d_in, const int* in_sizes, int n_in,
                              void* d_out, int out_size, void* d_ws, size_t ws_size,
                              hipStream_t stream)
{
    const float* arr   = (const float*)d_in[0];
    const float* cbook = (const float*)d_in[1];
    float* out = (float*)d_out;
    // 4096 chains, 4 chains (waves) per 256-thread block -> 1024 blocks
    viterbi_q<<<dim3(1024), dim3(256), 0, stream>>>(arr, cbook, out);
}

// Round 4
// 105.874 us; speedup vs baseline: 1.0413x; 1.0413x over previous
//
#include <hip/hip_runtime.h>

// Viterbi trellis quantizer: S=1024 states, K=2 (4 predecessors), CHUNK=4,
// block_size=16 -> T=64 steps/chain, B=4096 chains (16x16 blocks of 1024^2).
//
// One 64-lane wave per chain, 4 chains per 256-thread workgroup.
// beta-formulation: beta[s] = -(alpha[s] - sum||x||^2)/2 satisfies
//   beta_new[s] = max_j beta[prev_j(s)] + (cb[s]·x + h[s]),  h = -||cb||^2/2
// -> no per-step ||x||^2, no M+xn adds; FMA chain starts at h.
// Grouped-max state M[p] = max_j beta[p + 256 j] in LDS (argmin j of alpha
// == argmax j of beta; value never output, only traced states).
//
// R2 evidence: __launch_bounds__(256,4) only sets MIN waves/EU; allocator
// still chased 8 waves/EU (VGPR_Count=64) and, with the asm pin, SPILLED the
// codebook to scratch (WRITE_SIZE 5120->9216 KB). Grid is 4 blocks/CU so >4
// waves/EU is unreachable: amdgpu_waves_per_eu(4,4) tells the allocator the
// truth -> 128-reg budget, codebook (80 regs) stays resident.

#define COLS      1024
#define T_STEPS   64
#define REC_SIZE  (1024 * 1024)

__global__ __launch_bounds__(256)
__attribute__((amdgpu_waves_per_eu(4, 4)))
void viterbi_q(
    const float* __restrict__ arr,
    const float* __restrict__ cbook,
    float* __restrict__ out)
{
    const int tid   = threadIdx.x;
    const int wid   = tid >> 6;      // wave id in block = chain slot
    const int lane  = tid & 63;
    const int chain = (blockIdx.x << 2) | wid;   // 0..4095
    const int rb    = chain >> 6;    // block-row
    const int cb    = chain & 63;    // block-col

    __shared__ __align__(16) float tile[4][256];   // x chunks for the chain
    __shared__ __align__(16) float Mst[4][256];    // grouped-max state M[p]
    __shared__ unsigned char Jb[4][63 * 64];       // packed backpointers
    __shared__ int st_lds[4][64];                  // traced-back states

    // ---- stage this chain's 16x16 tile into LDS (tile[e], e = r*16 + c) ----
    {
        const int r  = lane >> 2;
        const int c4 = (lane & 3) << 2;
        float4 v = *(const float4*)(arr + (rb * 16 + r) * COLS + cb * 16 + c4);
        *(float4*)&tile[wid][lane << 2] = v;
    }
    // M starts at 0: iteration t=0 then computes beta0 = cb·x0 + h exactly.
    *(float4*)&Mst[wid][lane << 2] = make_float4(0.f, 0.f, 0.f, 0.f);

    // ---- codebook rows for this lane's 16 states: s = 4*lane + c + 256*j ----
    float4 a[16];   // raw codebook row
    float  h[16];   // -||row||^2 / 2
    #pragma unroll
    for (int j = 0; j < 4; ++j) {
        #pragma unroll
        for (int c = 0; c < 4; ++c) {
            const int row = (lane << 2) + c + (j << 8);
            float4 v = *(const float4*)(cbook + row * 4);
            a[j * 4 + c] = v;
            h[j * 4 + c] = -0.5f * (v.x * v.x + v.y * v.y +
                                    v.z * v.z + v.w * v.w);
        }
    }
    // Pin the codebook into VGPRs: empty asm "modifies" the values, so the
    // scheduler can neither rematerialize the loads nor sink them.
    #pragma unroll
    for (int j = 0; j < 4; ++j) {
        asm volatile(""
            : "+v"(a[j*4+0].x), "+v"(a[j*4+0].y), "+v"(a[j*4+0].z), "+v"(a[j*4+0].w),
              "+v"(a[j*4+1].x), "+v"(a[j*4+1].y), "+v"(a[j*4+1].z), "+v"(a[j*4+1].w),
              "+v"(a[j*4+2].x), "+v"(a[j*4+2].y), "+v"(a[j*4+2].z), "+v"(a[j*4+2].w),
              "+v"(a[j*4+3].x), "+v"(a[j*4+3].y), "+v"(a[j*4+3].z), "+v"(a[j*4+3].w),
              "+v"(h[j*4+0]), "+v"(h[j*4+1]), "+v"(h[j*4+2]), "+v"(h[j*4+3]));
    }

    // hoisted LDS pointers
    const float* __restrict__ tilep = &tile[wid][0];
    float* __restrict__ Mp          = &Mst[wid][0];
    unsigned char* __restrict__ Jp  = &Jb[wid][0];

    // ---- forward recursion, t = 0..62: store backpointers J_t ----
    #pragma unroll 1
    for (int t = 0; t < T_STEPS - 1; ++t) {
        float4 xt = *(const float4*)&tilep[t << 2];   // broadcast read
        float mj[4];
        #pragma unroll
        for (int j = 0; j < 4; ++j)
            mj[j] = Mp[lane + 64 * j];

        float nm[4];
        unsigned bp = 0;
        #pragma unroll
        for (int c = 0; c < 4; ++c) {
            float cand[4];
            #pragma unroll
            for (int j = 0; j < 4; ++j) {
                const float4 av = a[j * 4 + c];
                float acc = fmaf(av.x, xt.x, h[j * 4 + c]);
                acc = fmaf(av.y, xt.y, acc);
                acc = fmaf(av.z, xt.z, acc);
                acc = fmaf(av.w, xt.w, acc);
                cand[j] = acc + mj[j];
            }
            const float v = fmaxf(fmaxf(cand[0], cand[1]),
                                  fmaxf(cand[2], cand[3]));
            // first-max index == reference's first-min over alpha candidates
            const int j = (cand[0] == v) ? 0
                        : (cand[1] == v) ? 1
                        : (cand[2] == v) ? 2 : 3;
            nm[c] = v;
            bp |= (unsigned)j << (2 * c);
        }
        // wave-lockstep: all lanes issued their M reads above before this write
        *(float4*)&Mp[lane << 2] = make_float4(nm[0], nm[1], nm[2], nm[3]);
        Jp[t * 64 + lane] = (unsigned char)bp;
    }

    // ---- final step t = 63: full argmax over beta_63[0..1023] ----
    int bests;
    {
        const int t = T_STEPS - 1;
        float4 xt = *(const float4*)&tilep[t << 2];
        float mj[4];
        #pragma unroll
        for (int j = 0; j < 4; ++j)
            mj[j] = Mp[lane + 64 * j];

        float bv = -3.4e38f;
        int   bs = 0;
        #pragma unroll
        for (int j = 0; j < 4; ++j) {      // s ascends with (j, c): first-max ok
            #pragma unroll
            for (int c = 0; c < 4; ++c) {
                const float4 av = a[j * 4 + c];
                float acc = fmaf(av.x, xt.x, h[j * 4 + c]);
                acc = fmaf(av.y, xt.y, acc);
                acc = fmaf(av.z, xt.z, acc);
                acc = fmaf(av.w, xt.w, acc);
                acc += mj[j];
                if (acc > bv) { bv = acc; bs = (lane << 2) + c + (j << 8); }
            }
        }
        // lexicographic (value desc, state asc) butterfly across the wave
        #pragma unroll
        for (int off = 32; off > 0; off >>= 1) {
            const float ov = __shfl_xor(bv, off, 64);
            const int   os = __shfl_xor(bs, off, 64);
            if (ov > bv || (ov == bv && os < bs)) { bv = ov; bs = os; }
        }
        bests = bs;
    }

    // ---- traceback (serial, lane 0 of each wave) ----
    if (lane == 0) {
        int s = bests;
        st_lds[wid][T_STEPS - 1] = s;
        for (int i = T_STEPS - 2; i >= 0; --i) {
            const int p = s >> 2;
            const unsigned byte = Jp[i * 64 + (p >> 2)];
            const int j = (byte >> (2 * (p & 3))) & 3;
            s = p + (j << 8);
            st_lds[wid][i] = s;
        }
    }
    __syncthreads();

    // ---- outputs: lane i handles step t = i ----
    const int st = st_lds[wid][lane];
    // states_out flat: REC_SIZE + chain*64 + t   (stored as float values)
    out[REC_SIZE + chain * 64 + lane] = (float)st;
    // rec: step t covers elements e = 4t..4t+3 -> row t>>2, cols 4*(t&3)..+3
    const float4 v = *(const float4*)(cbook + st * 4);
    const int r  = lane >> 2;
    const int c4 = (lane & 3) << 2;
    *(float4*)(out + (rb * 16 + r) * COLS + cb * 16 + c4) = v;
}

extern "C" void kernel_launch(void* const* d_in, const int* in_sizes, int n_in,
                              void* d_out, int out_size, void* d_ws, size_t ws_size,
                              hipStream_t stream)
{
    const float* arr   = (const float*)d_in[0];
    const float* cbook = (const float*)d_in[1];
    float* out = (float*)d_out;
    // 4096 chains, 4 chains (waves) per 256-thread block -> 1024 blocks
    viterbi_q<<<dim3(1024), dim3(256), 0, stream>>>(arr, cbook, out);
}